// Round 16
// baseline (215.591 us; speedup 1.0000x reference)
//
#include <hip/hip_runtime.h>
#include <hip/hip_bf16.h>
#include <math.h>

// Output layout (floats):
//  image          [128,3,240,256]   off 0
//  names_idxs     [128,960,256]     off 23592960
//  p              [128,256,256]     off 55050240
//  attributes_idxs[128,240,8]       off 63438848
//  pal            [128,8,12]        off 63684608
#define O_IMG   0
#define O_NAMES 23592960ULL
#define O_P     55050240ULL
#define O_ATTR  63438848ULL
#define O_PAL   63684608ULL

typedef __attribute__((ext_vector_type(8))) short short8v;
typedef __attribute__((ext_vector_type(4))) float f32x4;

static __device__ inline unsigned short f2bf(float x) {
    __hip_bfloat16 h = __float2bfloat16(x);
    return *reinterpret_cast<unsigned short*>(&h);
}

// ---------------- pattern softmax, fully coalesced (+ bf16 P^T) ------------
template<bool WRITE_PT>
__global__ __launch_bounds__(256) void k_pattern2(const float* __restrict__ patterns,
                                                  float* __restrict__ out_p,
                                                  unsigned short* __restrict__ Pt) {
    int bp = blockIdx.x;
    int b  = bp >> 3;
    int pi = bp & 7;

    __shared__ float sP[4 * 16 * 136];          // [g][ti][136] (128 used)
    __shared__ unsigned short sR[32 * 264];     // [pj*4+g][264] (256 used)

    int tid = threadIdx.x;

    #pragma unroll
    for (int p = 0; p < 8; p++) {
        int li   = p * 256 + tid;       // (g, ti, col4)
        int col4 = li & 31;
        int ti   = (li >> 5) & 15;
        int g    = li >> 9;
        float4 v = *(const float4*)(patterns + (size_t)b * 65536 + g * 16384 +
                                    (ti * 8 + pi) * 128 + col4 * 4);
        *(float4*)&sP[(g * 16 + ti) * 136 + col4 * 4] = v;
    }
    __syncthreads();

    int pj = tid & 7;
    int nb = tid >> 3;     // 0..31
    #pragma unroll
    for (int i = 0; i < 8; i++) {
        int n  = nb * 8 + i;
        int ti = n >> 4, tj = n & 15;
        int base = ti * 136 + tj * 8 + pj;
        float v0 = sP[              base];
        float v1 = sP[16 * 136   + base];
        float v2 = sP[32 * 136   + base];
        float v3 = sP[48 * 136   + base];
        float m  = fmaxf(fmaxf(v0, v1), fmaxf(v2, v3));
        float e0 = __expf(v0 - m), e1 = __expf(v1 - m), e2 = __expf(v2 - m), e3 = __expf(v3 - m);
        float inv = 1.0f / (e0 + e1 + e2 + e3);
        float p0 = e0 * inv, p1 = e1 * inv, p2 = e2 * inv, p3 = e3 * inv;
        float4 r; r.x = p0; r.y = p1; r.z = p2; r.w = p3;
        *(float4*)(out_p + (size_t)(b * 256 + n) * 256 + pi * 32 + pj * 4) = r;
        if (WRITE_PT) {
            sR[(pj * 4 + 0) * 264 + n] = f2bf(p0);
            sR[(pj * 4 + 1) * 264 + n] = f2bf(p1);
            sR[(pj * 4 + 2) * 264 + n] = f2bf(p2);
            sR[(pj * 4 + 3) * 264 + n] = f2bf(p3);
        }
    }
    if (WRITE_PT) {
        __syncthreads();
        int n4  = tid & 63;
        int fl0 = tid >> 6;
        #pragma unroll
        for (int k = 0; k < 8; k++) {
            int fl = fl0 * 8 + k;      // 0..31
            short4 rv = *(short4*)&sR[fl * 264 + n4 * 4];
            *(short4*)(Pt + (size_t)b * 65536 + (size_t)(pi * 32 + fl) * 256 + n4 * 4) = rv;
        }
    }
}

// ---------------- names softmax (fallback path only) -----------------------
__global__ __launch_bounds__(256) void k_names(const float* __restrict__ names,
                                               const float* __restrict__ gumbel,
                                               float* __restrict__ out) {
    int chunk = blockIdx.x % 60;
    int b     = blockIdx.x / 60;
    int t0 = chunk * 16;
    __shared__ float sN[256 * 17];

    int q = threadIdx.x;
    const float* nb = names + (size_t)b * 245760 + t0;
    {
        int j  = q & 3;
        int n0 = q >> 2;
        #pragma unroll
        for (int pass = 0; pass < 4; pass++) {
            int n = n0 + 64 * pass;
            float4 v = *(const float4*)(nb + (size_t)n * 960 + 4 * j);
            float* dst = sN + n * 17 + 4 * j;
            dst[0] = v.x; dst[1] = v.y; dst[2] = v.z; dst[3] = v.w;
        }
    }
    __syncthreads();

    int lane = q & 63;
    int w    = q >> 6;
    const float* gb = gumbel + ((size_t)b * 960 + t0) * 256;
    float*       ob = out    + ((size_t)b * 960 + t0) * 256;

    #pragma unroll
    for (int tt = 0; tt < 4; tt++) {
        int t = w * 4 + tt;
        float v[4];
        #pragma unroll
        for (int k = 0; k < 4; k++) {
            int n = lane + 64 * k;
            v[k] = (sN[n * 17 + t] + gb[(size_t)t * 256 + n]) * 0.5f;
        }
        float m = fmaxf(fmaxf(v[0], v[1]), fmaxf(v[2], v[3]));
        #pragma unroll
        for (int off = 1; off < 64; off <<= 1) m = fmaxf(m, __shfl_xor(m, off));
        float s = 0.f;
        #pragma unroll
        for (int k = 0; k < 4; k++) { v[k] = expf(v[k] - m); s += v[k]; }
        #pragma unroll
        for (int off = 1; off < 64; off <<= 1) s += __shfl_xor(s, off);
        float inv = 1.0f / s;
        #pragma unroll
        for (int k = 0; k < 4; k++) ob[(size_t)t * 256 + lane + 64 * k] = v[k] * inv;
    }
}

// ---------------- attr softmax (8-wide) + pal copy -------------------------
__global__ __launch_bounds__(256) void k_attr(const float* __restrict__ attributes,
                                              const float* __restrict__ gumbel,
                                              const float* __restrict__ palettes,
                                              float* __restrict__ out_attr,
                                              float* __restrict__ out_pal) {
    int idx = blockIdx.x * 256 + threadIdx.x;
    if (idx < 12288) out_pal[idx] = palettes[idx];
    if (idx >= 128 * 240) return;
    int tb = idx % 240;
    int b  = idx / 240;
    float v[8];
    float m = -1e30f;
    #pragma unroll
    for (int e = 0; e < 8; e++) {
        v[e] = (attributes[((size_t)b * 8 + e) * 240 + tb] +
                gumbel[((size_t)b * 240 + tb) * 8 + e]) * 0.5f;
        m = fmaxf(m, v[e]);
    }
    float s = 0.f;
    #pragma unroll
    for (int e = 0; e < 8; e++) { v[e] = __expf(v[e] - m); s += v[e]; }
    float inv = 1.0f / s;
    float* o = out_attr + (size_t)idx * 8;
    #pragma unroll
    for (int e = 0; e < 8; e++) o[e] = v[e] * inv;
}

// ---------------- FUSED, BM=16 = the k_names block shape -------------------
// block = (b, 16-t chunk): phase A is R2's proven single-barrier softmax
// (17.4KB sN, 4 rows/wave) + bf16 sA write; phase B = K-loop acc[1][4];
// phase C = ONE sMono pass overlaid on dead sN. 26KB LDS -> 6 blocks/CU.
__global__ __launch_bounds__(256, 6) void k_fused(const float* __restrict__ names,
                                                  const float* __restrict__ gumbel,
                                                  const unsigned short* __restrict__ Pt,
                                                  const float* __restrict__ attr,
                                                  const float* __restrict__ pal,
                                                  float* __restrict__ out_names,
                                                  float* __restrict__ img) {
    // XCD-aware decode: j%8 = XCD; 120 chunks per XCD stay on one XCD.
    int j  = blockIdx.x;            // 0..7679
    int x  = j & 7;
    int s  = j >> 3;                // 0..959
    int q  = s / 60;                // 0..15
    int ch = s % 60;                // chunk 0..59
    int b  = x + 8 * q;             // 0..127
    int t0 = ch * 16;

    __shared__ __align__(16) char sA[8192];        // [16 t][512B] bf16 swizzled
    __shared__ __align__(16) float sN[256 * 17];   // names staging / sMono union
    __shared__ float sCol[96];                     // [8 tb][12]

    int tid  = threadIdx.x;
    int lane = tid & 63;
    int w    = tid >> 6;
    int lo   = lane & 15;
    int hi   = lane >> 4;

    int r    = ch >> 1;             // nametable row 0..29
    int cb16 = (ch & 1) * 16;       // column base within the 32-wide row

    // colorization table: 8 tb blocks covering this half-row
    if (tid < 96) {
        int tblL = tid / 12;        // 0..7
        int gc   = tid % 12;
        int tb   = (r >> 1) * 16 + (ch & 1) * 8 + tblL;
        const float* at = attr + ((size_t)b * 240 + tb) * 8;
        const float* pl = pal + (size_t)b * 96 + gc;
        float sum = 0.f;
        #pragma unroll
        for (int e = 0; e < 8; e++) sum += at[e] * pl[e * 12];
        sCol[tblL * 12 + gc] = sum;
    }

    // ---------- phase A: R2-exact names softmax (ONE stage barrier) --------
    const float* nb  = names + (size_t)b * 245760 + t0;
    const float* gb  = gumbel + ((size_t)b * 960 + t0) * 256;
    float*       onb = out_names + ((size_t)b * 960 + t0) * 256;
    {
        int jj = tid & 3;
        int n0 = tid >> 2;
        #pragma unroll
        for (int pass = 0; pass < 4; pass++) {
            int n = n0 + 64 * pass;
            float4 v = *(const float4*)(nb + (size_t)n * 960 + 4 * jj);
            float* dst = sN + n * 17 + 4 * jj;
            dst[0] = v.x; dst[1] = v.y; dst[2] = v.z; dst[3] = v.w;
        }
    }
    __syncthreads();

    #pragma unroll
    for (int tt = 0; tt < 4; tt++) {
        int t = w * 4 + tt;            // 0..15
        float v[4];
        #pragma unroll
        for (int k = 0; k < 4; k++) {
            int n = lane + 64 * k;
            v[k] = (sN[n * 17 + t] + gb[(size_t)t * 256 + n]) * 0.5f;   // /TAU
        }
        float m = fmaxf(fmaxf(v[0], v[1]), fmaxf(v[2], v[3]));
        #pragma unroll
        for (int off = 1; off < 64; off <<= 1) m = fmaxf(m, __shfl_xor(m, off));
        float sm = 0.f;
        #pragma unroll
        for (int k = 0; k < 4; k++) { v[k] = __expf(v[k] - m); sm += v[k]; }
        #pragma unroll
        for (int off = 1; off < 64; off <<= 1) sm += __shfl_xor(sm, off);
        float inv = 1.0f / sm;
        #pragma unroll
        for (int k = 0; k < 4; k++) {
            int n = lane + 64 * k;
            float p = v[k] * inv;
            onb[(size_t)t * 256 + n] = p;      // coalesced 256B/instr
            *(unsigned short*)(sA + ((t * 512 + n * 2) ^ ((t & 7) << 4))) = f2bf(p);
        }
    }
    __syncthreads();   // sA complete; all sN reads done (sMono may overlay)

    // ---------- phase B: K-loop (1-deep register prefetch) -----------------
    f32x4 acc[4];
    #pragma unroll
    for (int ni = 0; ni < 4; ni++) acc[ni] = (f32x4){0.f, 0.f, 0.f, 0.f};

    const unsigned short* Ptb = Pt + (size_t)b * 65536 + hi * 8;

    short8v bcur[4], bnxt[4];
    #pragma unroll
    for (int ni = 0; ni < 4; ni++) {
        int f = w * 64 + ni * 16 + lo;
        bcur[ni] = *(const short8v*)(Ptb + (size_t)f * 256);
    }

    #pragma unroll
    for (int k0 = 0; k0 < 256; k0 += 32) {
        if (k0 < 224) {
            #pragma unroll
            for (int ni = 0; ni < 4; ni++) {
                int f = w * 64 + ni * 16 + lo;
                bnxt[ni] = *(const short8v*)(Ptb + (size_t)f * 256 + k0 + 32);
            }
        }
        int ka = (k0 + hi * 8) * 2;
        short8v a0 = *(short8v*)(sA + ((lo * 512 + ka) ^ ((lo & 7) << 4)));
        #pragma unroll
        for (int ni = 0; ni < 4; ni++)
            acc[ni] = __builtin_amdgcn_mfma_f32_16x16x32_bf16(a0, bcur[ni], acc[ni], 0, 0, 0);
        if (k0 < 224) {
            #pragma unroll
            for (int ni = 0; ni < 4; ni++) bcur[ni] = bnxt[ni];
        }
    }

    // ---------- phase C: single epilogue pass (sMono overlays sN) ----------
    float* sMono = sN;                 // [16][260] padded stride
    #pragma unroll
    for (int ni = 0; ni < 4; ni++) {
        int colf = w * 64 + ni * 16 + lo;
        #pragma unroll
        for (int rg = 0; rg < 4; rg++)
            sMono[(hi * 4 + rg) * 260 + colf] = acc[ni][rg];
    }
    __syncthreads();

    int tf = tid & 63;
    int tm = tid >> 6;
    int pi = tf >> 3, pj = tf & 7;
    #pragma unroll
    for (int i = 0; i < 4; i++) {
        int ccl  = tm * 4 + i;          // 0..15
        int ccol = cb16 + ccl;          // column in nametable row
        int tblL = ccl >> 1;
        float4 mv = *(float4*)&sMono[ccl * 260 + tf * 4];
        #pragma unroll
        for (int c = 0; c < 3; c++) {
            float sv = mv.x * sCol[tblL * 12 + c]
                     + mv.y * sCol[tblL * 12 + 3 + c]
                     + mv.z * sCol[tblL * 12 + 6 + c]
                     + mv.w * sCol[tblL * 12 + 9 + c];
            float y = 1.0f / (1.0f + __expf(-sv));
            img[(((size_t)b * 3 + c) * 240 + r * 8 + pi) * 256 + ccol * 8 + pj] = y;
        }
    }
}

// ---------------- fp32 fallback image kernel (no ws) -----------------------
__global__ __launch_bounds__(256) void k_image_fp32(const float* __restrict__ A,
                                                    const float* __restrict__ P,
                                                    const float* __restrict__ attr,
                                                    const float* __restrict__ pal,
                                                    float* __restrict__ img) {
    int blk = blockIdx.x;
    int r = blk % 30;
    int b = blk / 30;
    int t0 = r * 32;

    __shared__ float sA[32][33];
    __shared__ float sB[32][256];
    __shared__ float sColF[16][12];

    int tid = threadIdx.x;
    if (tid < 192) {
        int tbl = tid / 12;
        int gc  = tid % 12;
        int tb  = (r >> 1) * 16 + tbl;
        const float* at = attr + ((size_t)b * 240 + tb) * 8;
        const float* pl = pal + (size_t)b * 96 + gc;
        float s = 0.f;
        #pragma unroll
        for (int e = 0; e < 8; e++) s += at[e] * pl[e * 12];
        sColF[tbl][gc] = s;
    }

    float acc[8][4];
    #pragma unroll
    for (int i = 0; i < 8; i++)
        #pragma unroll
        for (int j = 0; j < 4; j++) acc[i][j] = 0.f;

    int tf = tid & 63;
    int tm = tid >> 6;

    const float* Ab = A + ((size_t)b * 960 + t0) * 256;
    const float* Pb = P + (size_t)b * 65536;

    for (int k0 = 0; k0 < 256; k0 += 32) {
        __syncthreads();
        #pragma unroll
        for (int i = 0; i < 4; i++) {
            int li = tid + i * 256;
            int tl = li >> 5, kk = li & 31;
            sA[tl][kk] = Ab[(size_t)tl * 256 + k0 + kk];
        }
        #pragma unroll
        for (int i = 0; i < 8; i++) {
            int li = tid + i * 256;
            int kk = li >> 6, ff = (li & 63) * 4;
            *(float4*)&sB[kk][ff] = *(const float4*)&Pb[(size_t)(k0 + kk) * 256 + ff];
        }
        __syncthreads();
        #pragma unroll
        for (int kk = 0; kk < 32; kk++) {
            float4 bv = *(float4*)&sB[kk][tf * 4];
            #pragma unroll
            for (int i = 0; i < 8; i++) {
                float av = sA[tm * 8 + i][kk];
                acc[i][0] += av * bv.x;
                acc[i][1] += av * bv.y;
                acc[i][2] += av * bv.z;
                acc[i][3] += av * bv.w;
            }
        }
    }

    int pi = tf >> 3, pj = tf & 7;
    #pragma unroll
    for (int i = 0; i < 8; i++) {
        int cc  = tm * 8 + i;
        int tbl = cc >> 1;
        #pragma unroll
        for (int c = 0; c < 3; c++) {
            float s = acc[i][0] * sColF[tbl][c]
                    + acc[i][1] * sColF[tbl][3 + c]
                    + acc[i][2] * sColF[tbl][6 + c]
                    + acc[i][3] * sColF[tbl][9 + c];
            float y = 1.0f / (1.0f + expf(-s));
            img[(((size_t)b * 3 + c) * 240 + r * 8 + pi) * 256 + cc * 8 + pj] = y;
        }
    }
}

extern "C" void kernel_launch(void* const* d_in, const int* in_sizes, int n_in,
                              void* d_out, int out_size, void* d_ws, size_t ws_size,
                              hipStream_t stream) {
    const float* names       = (const float*)d_in[0];
    const float* patterns    = (const float*)d_in[1];
    const float* attributes  = (const float*)d_in[2];
    const float* palettes    = (const float*)d_in[3];
    const float* gumbel_n    = (const float*)d_in[4];
    const float* gumbel_a    = (const float*)d_in[5];
    float* out = (float*)d_out;

    float* out_img   = out + O_IMG;
    float* out_names = out + O_NAMES;
    float* out_p     = out + O_P;
    float* out_attr  = out + O_ATTR;
    float* out_pal   = out + O_PAL;

    const size_t PT_BYTES = 128ULL * 256 * 256 * 2;   // 16.78 MB bf16 P^T
    bool use_mfma = (ws_size >= PT_BYTES) && (d_ws != nullptr);

    if (use_mfma) {
        unsigned short* Pt = (unsigned short*)d_ws;
        k_pattern2<true><<<1024, 256, 0, stream>>>(patterns, out_p, Pt);
        k_attr<<<120, 256, 0, stream>>>(attributes, gumbel_a, palettes, out_attr, out_pal);
        k_fused<<<7680, 256, 0, stream>>>(names, gumbel_n, Pt, out_attr, palettes,
                                          out_names, out_img);
    } else {
        k_pattern2<false><<<1024, 256, 0, stream>>>(patterns, out_p, nullptr);
        k_names<<<128 * 60, 256, 0, stream>>>(names, gumbel_n, out_names);
        k_attr<<<120, 256, 0, stream>>>(attributes, gumbel_a, palettes, out_attr, out_pal);
        k_image_fp32<<<128 * 30, 256, 0, stream>>>(out_names, out_p, out_attr, palettes, out_img);
    }
}

// Round 17
// 180.027 us; speedup vs baseline: 1.1975x; 1.1975x over previous
//
#include <hip/hip_runtime.h>
#include <hip/hip_bf16.h>
#include <math.h>

// Output layout (floats):
//  image          [128,3,240,256]   off 0
//  names_idxs     [128,960,256]     off 23592960
//  p              [128,256,256]     off 55050240
//  attributes_idxs[128,240,8]       off 63438848
//  pal            [128,8,12]        off 63684608
#define O_IMG   0
#define O_NAMES 23592960ULL
#define O_P     55050240ULL
#define O_ATTR  63438848ULL
#define O_PAL   63684608ULL

typedef __attribute__((ext_vector_type(8))) short short8v;
typedef __attribute__((ext_vector_type(4))) float f32x4;

static __device__ inline unsigned short f2bf(float x) {
    __hip_bfloat16 h = __float2bfloat16(x);
    return *reinterpret_cast<unsigned short*>(&h);
}

// ---------------- pattern softmax, fully coalesced (+ bf16 P^T) ------------
template<bool WRITE_PT>
__global__ __launch_bounds__(256) void k_pattern2(const float* __restrict__ patterns,
                                                  float* __restrict__ out_p,
                                                  unsigned short* __restrict__ Pt) {
    int bp = blockIdx.x;
    int b  = bp >> 3;
    int pi = bp & 7;

    __shared__ float sP[4 * 16 * 136];          // [g][ti][136] (128 used)
    __shared__ unsigned short sR[32 * 264];     // [pj*4+g][264] (256 used)

    int tid = threadIdx.x;

    #pragma unroll
    for (int p = 0; p < 8; p++) {
        int li   = p * 256 + tid;       // (g, ti, col4)
        int col4 = li & 31;
        int ti   = (li >> 5) & 15;
        int g    = li >> 9;
        float4 v = *(const float4*)(patterns + (size_t)b * 65536 + g * 16384 +
                                    (ti * 8 + pi) * 128 + col4 * 4);
        *(float4*)&sP[(g * 16 + ti) * 136 + col4 * 4] = v;
    }
    __syncthreads();

    int pj = tid & 7;
    int nb = tid >> 3;     // 0..31
    #pragma unroll
    for (int i = 0; i < 8; i++) {
        int n  = nb * 8 + i;
        int ti = n >> 4, tj = n & 15;
        int base = ti * 136 + tj * 8 + pj;
        float v0 = sP[              base];
        float v1 = sP[16 * 136   + base];
        float v2 = sP[32 * 136   + base];
        float v3 = sP[48 * 136   + base];
        float m  = fmaxf(fmaxf(v0, v1), fmaxf(v2, v3));
        float e0 = __expf(v0 - m), e1 = __expf(v1 - m), e2 = __expf(v2 - m), e3 = __expf(v3 - m);
        float inv = 1.0f / (e0 + e1 + e2 + e3);
        float p0 = e0 * inv, p1 = e1 * inv, p2 = e2 * inv, p3 = e3 * inv;
        float4 r; r.x = p0; r.y = p1; r.z = p2; r.w = p3;
        *(float4*)(out_p + (size_t)(b * 256 + n) * 256 + pi * 32 + pj * 4) = r;
        if (WRITE_PT) {
            sR[(pj * 4 + 0) * 264 + n] = f2bf(p0);
            sR[(pj * 4 + 1) * 264 + n] = f2bf(p1);
            sR[(pj * 4 + 2) * 264 + n] = f2bf(p2);
            sR[(pj * 4 + 3) * 264 + n] = f2bf(p3);
        }
    }
    if (WRITE_PT) {
        __syncthreads();
        int n4  = tid & 63;
        int fl0 = tid >> 6;
        #pragma unroll
        for (int k = 0; k < 8; k++) {
            int fl = fl0 * 8 + k;      // 0..31
            short4 rv = *(short4*)&sR[fl * 264 + n4 * 4];
            *(short4*)(Pt + (size_t)b * 65536 + (size_t)(pi * 32 + fl) * 256 + n4 * 4) = rv;
        }
    }
}

// ---------------- names softmax (fallback path only) -----------------------
__global__ __launch_bounds__(256) void k_names(const float* __restrict__ names,
                                               const float* __restrict__ gumbel,
                                               float* __restrict__ out) {
    int chunk = blockIdx.x % 60;
    int b     = blockIdx.x / 60;
    int t0 = chunk * 16;
    __shared__ float sN[256 * 17];

    int q = threadIdx.x;
    const float* nb = names + (size_t)b * 245760 + t0;
    {
        int j  = q & 3;
        int n0 = q >> 2;
        #pragma unroll
        for (int pass = 0; pass < 4; pass++) {
            int n = n0 + 64 * pass;
            float4 v = *(const float4*)(nb + (size_t)n * 960 + 4 * j);
            float* dst = sN + n * 17 + 4 * j;
            dst[0] = v.x; dst[1] = v.y; dst[2] = v.z; dst[3] = v.w;
        }
    }
    __syncthreads();

    int lane = q & 63;
    int w    = q >> 6;
    const float* gb = gumbel + ((size_t)b * 960 + t0) * 256;
    float*       ob = out    + ((size_t)b * 960 + t0) * 256;

    #pragma unroll
    for (int tt = 0; tt < 4; tt++) {
        int t = w * 4 + tt;
        float v[4];
        #pragma unroll
        for (int k = 0; k < 4; k++) {
            int n = lane + 64 * k;
            v[k] = (sN[n * 17 + t] + gb[(size_t)t * 256 + n]) * 0.5f;
        }
        float m = fmaxf(fmaxf(v[0], v[1]), fmaxf(v[2], v[3]));
        #pragma unroll
        for (int off = 1; off < 64; off <<= 1) m = fmaxf(m, __shfl_xor(m, off));
        float s = 0.f;
        #pragma unroll
        for (int k = 0; k < 4; k++) { v[k] = expf(v[k] - m); s += v[k]; }
        #pragma unroll
        for (int off = 1; off < 64; off <<= 1) s += __shfl_xor(s, off);
        float inv = 1.0f / s;
        #pragma unroll
        for (int k = 0; k < 4; k++) ob[(size_t)t * 256 + lane + 64 * k] = v[k] * inv;
    }
}

// ---------------- attr softmax (8-wide) + pal copy -------------------------
__global__ __launch_bounds__(256) void k_attr(const float* __restrict__ attributes,
                                              const float* __restrict__ gumbel,
                                              const float* __restrict__ palettes,
                                              float* __restrict__ out_attr,
                                              float* __restrict__ out_pal) {
    int idx = blockIdx.x * 256 + threadIdx.x;
    if (idx < 12288) out_pal[idx] = palettes[idx];
    if (idx >= 128 * 240) return;
    int tb = idx % 240;
    int b  = idx / 240;
    float v[8];
    float m = -1e30f;
    #pragma unroll
    for (int e = 0; e < 8; e++) {
        v[e] = (attributes[((size_t)b * 8 + e) * 240 + tb] +
                gumbel[((size_t)b * 240 + tb) * 8 + e]) * 0.5f;
        m = fmaxf(m, v[e]);
    }
    float s = 0.f;
    #pragma unroll
    for (int e = 0; e < 8; e++) { v[e] = __expf(v[e] - m); s += v[e]; }
    float inv = 1.0f / s;
    float* o = out_attr + (size_t)idx * 8;
    #pragma unroll
    for (int e = 0; e < 8; e++) o[e] = v[e] * inv;
}

// ======= phase-A body (names softmax, 4 chunks of 8 rows, sN2 8.7KB) =======
template<bool WRITE_SA>
__device__ __forceinline__ void phaseA(const float* __restrict__ nb,
                                       const float* __restrict__ gb,
                                       float* __restrict__ onb,
                                       char* smem, float* sN2,
                                       int tid, int lane, int w) {
    int jj2 = tid & 1;
    int n0  = tid >> 1;          // 0..127

    float4 rbuf[2][2];
    #pragma unroll
    for (int p = 0; p < 2; p++)
        rbuf[0][p] = *(const float4*)(nb + (size_t)(n0 + 128 * p) * 960 + 4 * jj2);

    #pragma unroll
    for (int c = 0; c < 4; c++) {
        #pragma unroll
        for (int p = 0; p < 2; p++) {
            int n = n0 + 128 * p;
            float4 rv = rbuf[c & 1][p];
            sN2[(4 * jj2 + 0) * 272 + n] = rv.x;
            sN2[(4 * jj2 + 1) * 272 + n] = rv.y;
            sN2[(4 * jj2 + 2) * 272 + n] = rv.z;
            sN2[(4 * jj2 + 3) * 272 + n] = rv.w;
        }
        if (c < 3) {
            #pragma unroll
            for (int p = 0; p < 2; p++)
                rbuf[(c + 1) & 1][p] =
                    *(const float4*)(nb + (size_t)(n0 + 128 * p) * 960 + (c + 1) * 8 + 4 * jj2);
        }
        __syncthreads();

        f32x4 gv[2];
        #pragma unroll
        for (int tt = 0; tt < 2; tt++) {
            int tl = c * 8 + w * 2 + tt;
            gv[tt] = *(const f32x4*)(gb + (size_t)tl * 256 + lane * 4);
        }
        #pragma unroll
        for (int tt = 0; tt < 2; tt++) {
            int trow = w * 2 + tt;          // 0..7
            int tl   = c * 8 + trow;        // 0..31
            f32x4 nv = *(const f32x4*)&sN2[trow * 272 + lane * 4];
            float v[4];
            #pragma unroll
            for (int k = 0; k < 4; k++) v[k] = (nv[k] + gv[tt][k]) * 0.5f;   // /TAU
            float m = fmaxf(fmaxf(v[0], v[1]), fmaxf(v[2], v[3]));
            #pragma unroll
            for (int off = 1; off < 64; off <<= 1) m = fmaxf(m, __shfl_xor(m, off));
            float sm = 0.f;
            #pragma unroll
            for (int k = 0; k < 4; k++) { v[k] = __expf(v[k] - m); sm += v[k]; }
            #pragma unroll
            for (int off = 1; off < 64; off <<= 1) sm += __shfl_xor(sm, off);
            float inv = 1.0f / sm;
            f32x4 pv;
            #pragma unroll
            for (int k = 0; k < 4; k++) pv[k] = v[k] * inv;
            *(f32x4*)(onb + (size_t)tl * 256 + lane * 4) = pv;   // 16B store
            if (WRITE_SA) {
                unsigned long long hv =
                      (unsigned long long)f2bf(pv[0])
                    | ((unsigned long long)f2bf(pv[1]) << 16)
                    | ((unsigned long long)f2bf(pv[2]) << 32)
                    | ((unsigned long long)f2bf(pv[3]) << 48);
                *(unsigned long long*)(smem + ((tl * 512 + lane * 8) ^ ((tl & 7) << 4))) = hv;
            }
        }
        __syncthreads();   // sN2 reads done before next chunk's overwrite
    }
}

// ---------------- FUSED names-softmax + MFMA GEMM + colorize, BM=32 --------
// 25.8 KB LDS -> 6 blocks/CU (24 waves, ~59% occ). R14 kernel, probe removed.
__global__ __launch_bounds__(256, 6) void k_fused(const float* __restrict__ names,
                                                  const float* __restrict__ gumbel,
                                                  const unsigned short* __restrict__ Pt,
                                                  const float* __restrict__ attr,
                                                  const float* __restrict__ pal,
                                                  float* __restrict__ out_names,
                                                  float* __restrict__ img) {
    // XCD-aware decode: j%8 = XCD; batches b with b%8==x stay on XCD x.
    int j  = blockIdx.x;
    int x  = j & 7;
    int s  = j >> 3;          // 0..479
    int q  = s / 30;
    int rr = s % 30;          // nametable row 0..29
    int b  = x + 8 * q;       // 0..127
    int t0 = rr * 32;

    __shared__ __align__(16) char smem[16896];    // sA [32][512B] / sMono [16][260]f
    __shared__ __align__(16) float sN2[8 * 272];  // names transpose (8.7 KB)
    __shared__ float sCol[192];                   // [16][12]

    int tid  = threadIdx.x;
    int lane = tid & 63;
    int w    = tid >> 6;
    int lo   = lane & 15;
    int hi   = lane >> 4;

    // colorization table
    if (tid < 192) {
        int tbl = tid / 12;
        int gc  = tid % 12;
        int tb  = (rr >> 1) * 16 + tbl;
        const float* at = attr + ((size_t)b * 240 + tb) * 8;
        const float* pl = pal + (size_t)b * 96 + gc;
        float sum = 0.f;
        #pragma unroll
        for (int e = 0; e < 8; e++) sum += at[e] * pl[e * 12];
        sCol[tbl * 12 + gc] = sum;
    }

    // ---------- phase A ----------------------------------------------------
    const float* nb  = names + (size_t)b * 245760 + t0;
    const float* gb  = gumbel + ((size_t)b * 960 + t0) * 256;
    float*       onb = out_names + ((size_t)b * 960 + t0) * 256;
    phaseA<true>(nb, gb, onb, smem, sN2, tid, lane, w);
    __syncthreads();   // sA complete

    // ---------- phase B: K-loop (1-deep prefetch) --------------------------
    f32x4 acc[2][4];
    #pragma unroll
    for (int mi = 0; mi < 2; mi++)
        #pragma unroll
        for (int ni = 0; ni < 4; ni++) acc[mi][ni] = (f32x4){0.f, 0.f, 0.f, 0.f};

    const unsigned short* Ptb = Pt + (size_t)b * 65536 + hi * 8;

    short8v bcur[4], bnxt[4];
    #pragma unroll
    for (int ni = 0; ni < 4; ni++) {
        int f = w * 64 + ni * 16 + lo;
        bcur[ni] = *(const short8v*)(Ptb + (size_t)f * 256);
    }

    #pragma unroll
    for (int k0 = 0; k0 < 256; k0 += 32) {
        if (k0 < 224) {
            #pragma unroll
            for (int ni = 0; ni < 4; ni++) {
                int f = w * 64 + ni * 16 + lo;
                bnxt[ni] = *(const short8v*)(Ptb + (size_t)f * 256 + k0 + 32);
            }
        }
        int ka = (k0 + hi * 8) * 2;
        short8v a0 = *(short8v*)(smem + (((lo      ) * 512 + ka) ^ ((lo & 7) << 4)));
        short8v a1 = *(short8v*)(smem + (((lo + 16) * 512 + ka) ^ ((lo & 7) << 4)));
        #pragma unroll
        for (int ni = 0; ni < 4; ni++) {
            acc[0][ni] = __builtin_amdgcn_mfma_f32_16x16x32_bf16(a0, bcur[ni], acc[0][ni], 0, 0, 0);
            acc[1][ni] = __builtin_amdgcn_mfma_f32_16x16x32_bf16(a1, bcur[ni], acc[1][ni], 0, 0, 0);
        }
        if (k0 < 224) {
            #pragma unroll
            for (int ni = 0; ni < 4; ni++) bcur[ni] = bnxt[ni];
        }
    }

    // ---------- phase C: epilogue, 2 phases of 16 rows ---------------------
    float* sMono = (float*)smem;      // [16][260] padded stride
    int tf = tid & 63;
    int tm = tid >> 6;
    int pi = tf >> 3, pj = tf & 7;

    #pragma unroll
    for (int mi = 0; mi < 2; mi++) {
        __syncthreads();   // prior reads of smem done
        #pragma unroll
        for (int ni = 0; ni < 4; ni++) {
            int colf = w * 64 + ni * 16 + lo;
            #pragma unroll
            for (int rg = 0; rg < 4; rg++)
                sMono[(hi * 4 + rg) * 260 + colf] = acc[mi][ni][rg];
        }
        __syncthreads();
        int cbase = mi * 16;
        #pragma unroll
        for (int i = 0; i < 4; i++) {
            int ccl  = tm * 4 + i;          // 0..15
            int ccol = cbase + ccl;         // 0..31
            int tbl  = ccol >> 1;
            float4 mv = *(float4*)&sMono[ccl * 260 + tf * 4];
            #pragma unroll
            for (int c = 0; c < 3; c++) {
                float sv = mv.x * sCol[tbl * 12 + c]
                         + mv.y * sCol[tbl * 12 + 3 + c]
                         + mv.z * sCol[tbl * 12 + 6 + c]
                         + mv.w * sCol[tbl * 12 + 9 + c];
                float y = 1.0f / (1.0f + __expf(-sv));
                img[(((size_t)b * 3 + c) * 240 + rr * 8 + pi) * 256 + ccol * 8 + pj] = y;
            }
        }
    }
}

// ---------------- fp32 fallback image kernel (no ws) -----------------------
__global__ __launch_bounds__(256) void k_image_fp32(const float* __restrict__ A,
                                                    const float* __restrict__ P,
                                                    const float* __restrict__ attr,
                                                    const float* __restrict__ pal,
                                                    float* __restrict__ img) {
    int blk = blockIdx.x;
    int r = blk % 30;
    int b = blk / 30;
    int t0 = r * 32;

    __shared__ float sA[32][33];
    __shared__ float sB[32][256];
    __shared__ float sColF[16][12];

    int tid = threadIdx.x;
    if (tid < 192) {
        int tbl = tid / 12;
        int gc  = tid % 12;
        int tb  = (r >> 1) * 16 + tbl;
        const float* at = attr + ((size_t)b * 240 + tb) * 8;
        const float* pl = pal + (size_t)b * 96 + gc;
        float s = 0.f;
        #pragma unroll
        for (int e = 0; e < 8; e++) s += at[e] * pl[e * 12];
        sColF[tbl][gc] = s;
    }

    float acc[8][4];
    #pragma unroll
    for (int i = 0; i < 8; i++)
        #pragma unroll
        for (int j = 0; j < 4; j++) acc[i][j] = 0.f;

    int tf = tid & 63;
    int tm = tid >> 6;

    const float* Ab = A + ((size_t)b * 960 + t0) * 256;
    const float* Pb = P + (size_t)b * 65536;

    for (int k0 = 0; k0 < 256; k0 += 32) {
        __syncthreads();
        #pragma unroll
        for (int i = 0; i < 4; i++) {
            int li = tid + i * 256;
            int tl = li >> 5, kk = li & 31;
            sA[tl][kk] = Ab[(size_t)tl * 256 + k0 + kk];
        }
        #pragma unroll
        for (int i = 0; i < 8; i++) {
            int li = tid + i * 256;
            int kk = li >> 6, ff = (li & 63) * 4;
            *(float4*)&sB[kk][ff] = *(const float4*)&Pb[(size_t)(k0 + kk) * 256 + ff];
        }
        __syncthreads();
        #pragma unroll
        for (int kk = 0; kk < 32; kk++) {
            float4 bv = *(float4*)&sB[kk][tf * 4];
            #pragma unroll
            for (int i = 0; i < 8; i++) {
                float av = sA[tm * 8 + i][kk];
                acc[i][0] += av * bv.x;
                acc[i][1] += av * bv.y;
                acc[i][2] += av * bv.z;
                acc[i][3] += av * bv.w;
            }
        }
    }

    int pi = tf >> 3, pj = tf & 7;
    #pragma unroll
    for (int i = 0; i < 8; i++) {
        int cc  = tm * 8 + i;
        int tbl = cc >> 1;
        #pragma unroll
        for (int c = 0; c < 3; c++) {
            float s = acc[i][0] * sColF[tbl][c]
                    + acc[i][1] * sColF[tbl][3 + c]
                    + acc[i][2] * sColF[tbl][6 + c]
                    + acc[i][3] * sColF[tbl][9 + c];
            float y = 1.0f / (1.0f + expf(-s));
            img[(((size_t)b * 3 + c) * 240 + r * 8 + pi) * 256 + cc * 8 + pj] = y;
        }
    }
}

extern "C" void kernel_launch(void* const* d_in, const int* in_sizes, int n_in,
                              void* d_out, int out_size, void* d_ws, size_t ws_size,
                              hipStream_t stream) {
    const float* names       = (const float*)d_in[0];
    const float* patterns    = (const float*)d_in[1];
    const float* attributes  = (const float*)d_in[2];
    const float* palettes    = (const float*)d_in[3];
    const float* gumbel_n    = (const float*)d_in[4];
    const float* gumbel_a    = (const float*)d_in[5];
    float* out = (float*)d_out;

    float* out_img   = out + O_IMG;
    float* out_names = out + O_NAMES;
    float* out_p     = out + O_P;
    float* out_attr  = out + O_ATTR;
    float* out_pal   = out + O_PAL;

    const size_t PT_BYTES = 128ULL * 256 * 256 * 2;   // 16.78 MB bf16 P^T
    bool use_mfma = (ws_size >= PT_BYTES) && (d_ws != nullptr);

    if (use_mfma) {
        unsigned short* Pt = (unsigned short*)d_ws;
        k_pattern2<true><<<1024, 256, 0, stream>>>(patterns, out_p, Pt);
        k_attr<<<120, 256, 0, stream>>>(attributes, gumbel_a, palettes, out_attr, out_pal);
        k_fused<<<3840, 256, 0, stream>>>(names, gumbel_n, Pt, out_attr, palettes,
                                          out_names, out_img);
    } else {
        k_pattern2<false><<<1024, 256, 0, stream>>>(patterns, out_p, nullptr);
        k_names<<<128 * 60, 256, 0, stream>>>(names, gumbel_n, out_names);
        k_attr<<<120, 256, 0, stream>>>(attributes, gumbel_a, palettes, out_attr, out_pal);
        k_image_fp32<<<128 * 30, 256, 0, stream>>>(out_names, out_p, out_attr, palettes, out_img);
    }
}

// Round 18
// 162.577 us; speedup vs baseline: 1.3261x; 1.1073x over previous
//
#include <hip/hip_runtime.h>
#include <hip/hip_bf16.h>
#include <math.h>

// Output layout (floats):
//  image          [128,3,240,256]   off 0
//  names_idxs     [128,960,256]     off 23592960
//  p              [128,256,256]     off 55050240
//  attributes_idxs[128,240,8]       off 63438848
//  pal            [128,8,12]        off 63684608
#define O_IMG   0
#define O_NAMES 23592960ULL
#define O_P     55050240ULL
#define O_ATTR  63438848ULL
#define O_PAL   63684608ULL

typedef __attribute__((ext_vector_type(8))) short short8v;
typedef __attribute__((ext_vector_type(4))) float f32x4;

static __device__ inline unsigned short f2bf(float x) {
    __hip_bfloat16 h = __float2bfloat16(x);
    return *reinterpret_cast<unsigned short*>(&h);
}

// ---------------- pattern softmax, fully coalesced (+ bf16 P^T) ------------
template<bool WRITE_PT>
__global__ __launch_bounds__(256) void k_pattern2(const float* __restrict__ patterns,
                                                  float* __restrict__ out_p,
                                                  unsigned short* __restrict__ Pt) {
    int bp = blockIdx.x;
    int b  = bp >> 3;
    int pi = bp & 7;

    __shared__ float sP[4 * 16 * 136];          // [g][ti][136] (128 used)
    __shared__ unsigned short sR[32 * 264];     // [pj*4+g][264] (256 used)

    int tid = threadIdx.x;

    #pragma unroll
    for (int p = 0; p < 8; p++) {
        int li   = p * 256 + tid;       // (g, ti, col4)
        int col4 = li & 31;
        int ti   = (li >> 5) & 15;
        int g    = li >> 9;
        float4 v = *(const float4*)(patterns + (size_t)b * 65536 + g * 16384 +
                                    (ti * 8 + pi) * 128 + col4 * 4);
        *(float4*)&sP[(g * 16 + ti) * 136 + col4 * 4] = v;
    }
    __syncthreads();

    int pj = tid & 7;
    int nb = tid >> 3;     // 0..31
    #pragma unroll
    for (int i = 0; i < 8; i++) {
        int n  = nb * 8 + i;
        int ti = n >> 4, tj = n & 15;
        int base = ti * 136 + tj * 8 + pj;
        float v0 = sP[              base];
        float v1 = sP[16 * 136   + base];
        float v2 = sP[32 * 136   + base];
        float v3 = sP[48 * 136   + base];
        float m  = fmaxf(fmaxf(v0, v1), fmaxf(v2, v3));
        float e0 = __expf(v0 - m), e1 = __expf(v1 - m), e2 = __expf(v2 - m), e3 = __expf(v3 - m);
        float inv = 1.0f / (e0 + e1 + e2 + e3);
        float p0 = e0 * inv, p1 = e1 * inv, p2 = e2 * inv, p3 = e3 * inv;
        float4 r; r.x = p0; r.y = p1; r.z = p2; r.w = p3;
        *(float4*)(out_p + (size_t)(b * 256 + n) * 256 + pi * 32 + pj * 4) = r;
        if (WRITE_PT) {
            sR[(pj * 4 + 0) * 264 + n] = f2bf(p0);
            sR[(pj * 4 + 1) * 264 + n] = f2bf(p1);
            sR[(pj * 4 + 2) * 264 + n] = f2bf(p2);
            sR[(pj * 4 + 3) * 264 + n] = f2bf(p3);
        }
    }
    if (WRITE_PT) {
        __syncthreads();
        int n4  = tid & 63;
        int fl0 = tid >> 6;
        #pragma unroll
        for (int k = 0; k < 8; k++) {
            int fl = fl0 * 8 + k;      // 0..31
            short4 rv = *(short4*)&sR[fl * 264 + n4 * 4];
            *(short4*)(Pt + (size_t)b * 65536 + (size_t)(pi * 32 + fl) * 256 + n4 * 4) = rv;
        }
    }
}

// ---------------- names softmax (fallback path only) -----------------------
__global__ __launch_bounds__(256) void k_names(const float* __restrict__ names,
                                               const float* __restrict__ gumbel,
                                               float* __restrict__ out) {
    int chunk = blockIdx.x % 60;
    int b     = blockIdx.x / 60;
    int t0 = chunk * 16;
    __shared__ float sN[256 * 17];

    int q = threadIdx.x;
    const float* nb = names + (size_t)b * 245760 + t0;
    {
        int j  = q & 3;
        int n0 = q >> 2;
        #pragma unroll
        for (int pass = 0; pass < 4; pass++) {
            int n = n0 + 64 * pass;
            float4 v = *(const float4*)(nb + (size_t)n * 960 + 4 * j);
            float* dst = sN + n * 17 + 4 * j;
            dst[0] = v.x; dst[1] = v.y; dst[2] = v.z; dst[3] = v.w;
        }
    }
    __syncthreads();

    int lane = q & 63;
    int w    = q >> 6;
    const float* gb = gumbel + ((size_t)b * 960 + t0) * 256;
    float*       ob = out    + ((size_t)b * 960 + t0) * 256;

    #pragma unroll
    for (int tt = 0; tt < 4; tt++) {
        int t = w * 4 + tt;
        float v[4];
        #pragma unroll
        for (int k = 0; k < 4; k++) {
            int n = lane + 64 * k;
            v[k] = (sN[n * 17 + t] + gb[(size_t)t * 256 + n]) * 0.5f;
        }
        float m = fmaxf(fmaxf(v[0], v[1]), fmaxf(v[2], v[3]));
        #pragma unroll
        for (int off = 1; off < 64; off <<= 1) m = fmaxf(m, __shfl_xor(m, off));
        float s = 0.f;
        #pragma unroll
        for (int k = 0; k < 4; k++) { v[k] = expf(v[k] - m); s += v[k]; }
        #pragma unroll
        for (int off = 1; off < 64; off <<= 1) s += __shfl_xor(s, off);
        float inv = 1.0f / s;
        #pragma unroll
        for (int k = 0; k < 4; k++) ob[(size_t)t * 256 + lane + 64 * k] = v[k] * inv;
    }
}

// ---------------- attr softmax (8-wide) + pal copy -------------------------
__global__ __launch_bounds__(256) void k_attr(const float* __restrict__ attributes,
                                              const float* __restrict__ gumbel,
                                              const float* __restrict__ palettes,
                                              float* __restrict__ out_attr,
                                              float* __restrict__ out_pal) {
    int idx = blockIdx.x * 256 + threadIdx.x;
    if (idx < 12288) out_pal[idx] = palettes[idx];
    if (idx >= 128 * 240) return;
    int tb = idx % 240;
    int b  = idx / 240;
    float v[8];
    float m = -1e30f;
    #pragma unroll
    for (int e = 0; e < 8; e++) {
        v[e] = (attributes[((size_t)b * 8 + e) * 240 + tb] +
                gumbel[((size_t)b * 240 + tb) * 8 + e]) * 0.5f;
        m = fmaxf(m, v[e]);
    }
    float s = 0.f;
    #pragma unroll
    for (int e = 0; e < 8; e++) { v[e] = __expf(v[e] - m); s += v[e]; }
    float inv = 1.0f / s;
    float* o = out_attr + (size_t)idx * 8;
    #pragma unroll
    for (int e = 0; e < 8; e++) o[e] = v[e] * inv;
}

// ---------------- FUSED names-softmax + MFMA GEMM + colorize, BM=32 --------
// R13 configuration (best measured: 162.8 us total).
// Phase A fully VECTORIZED: lane owns n = 4*lane..4*lane+3 -> gumbel load,
// sN2 read, out_names store are 16B; sA bf16 write is one 8B op. sN2 is
// transposed [trow][272] (rows 16B-aligned; b128 reads conflict-free).
__global__ __launch_bounds__(256, 4) void k_fused(const float* __restrict__ names,
                                                  const float* __restrict__ gumbel,
                                                  const unsigned short* __restrict__ Pt,
                                                  const float* __restrict__ attr,
                                                  const float* __restrict__ pal,
                                                  float* __restrict__ out_names,
                                                  float* __restrict__ img) {
    // XCD-aware decode: j%8 = XCD; batches b with b%8==x stay on XCD x.
    int j  = blockIdx.x;
    int x  = j & 7;
    int s  = j >> 3;          // 0..479
    int q  = s / 30;
    int rr = s % 30;          // nametable row 0..29
    int b  = x + 8 * q;       // 0..127
    int t0 = rr * 32;

    __shared__ __align__(16) char smem[16896];   // sA [32][512B] / sMono [16][260]f
    __shared__ __align__(16) float sN2[16 * 272];// names transpose [trow][272]
    __shared__ float sCol[192];                  // [16][12]

    int tid  = threadIdx.x;
    int lane = tid & 63;
    int w    = tid >> 6;
    int lo   = lane & 15;
    int hi   = lane >> 4;

    // colorization table
    if (tid < 192) {
        int tbl = tid / 12;
        int gc  = tid % 12;
        int tb  = (rr >> 1) * 16 + tbl;
        const float* at = attr + ((size_t)b * 240 + tb) * 8;
        const float* pl = pal + (size_t)b * 96 + gc;
        float sum = 0.f;
        #pragma unroll
        for (int e = 0; e < 8; e++) sum += at[e] * pl[e * 12];
        sCol[tbl * 12 + gc] = sum;
    }

    // ---------- phase A: names softmax for 32 t-rows, 2 chunks of 16 ------
    const float* nb  = names + (size_t)b * 245760 + t0;
    const float* gb  = gumbel + ((size_t)b * 960 + t0) * 256;
    float*       onb = out_names + ((size_t)b * 960 + t0) * 256;

    int jj = tid & 3;
    int n0 = tid >> 2;

    f32x4 r0[4], r1[4];
    #pragma unroll
    for (int p = 0; p < 4; p++)
        r0[p] = *(const f32x4*)(nb + (size_t)(n0 + 64 * p) * 960 + 4 * jj);
    #pragma unroll
    for (int p = 0; p < 4; p++) {
        int n = n0 + 64 * p;
        #pragma unroll
        for (int e = 0; e < 4; e++) sN2[(4 * jj + e) * 272 + n] = r0[p][e];
    }
    // issue chunk1 names NOW — in flight under chunk0 softmax
    #pragma unroll
    for (int p = 0; p < 4; p++)
        r1[p] = *(const f32x4*)(nb + (size_t)(n0 + 64 * p) * 960 + 16 + 4 * jj);
    __syncthreads();

    #pragma unroll
    for (int c = 0; c < 2; c++) {
        // batched gumbel prefetch: 4 x 16B per wave-row
        f32x4 gv[4];
        #pragma unroll
        for (int tt = 0; tt < 4; tt++) {
            int tl = c * 16 + w * 4 + tt;
            gv[tt] = *(const f32x4*)(gb + (size_t)tl * 256 + lane * 4);
        }
        #pragma unroll
        for (int tt = 0; tt < 4; tt++) {
            int trow = w * 4 + tt;         // row within chunk (0..15)
            int tl   = c * 16 + trow;      // t_local in block (0..31)
            f32x4 nv = *(const f32x4*)&sN2[trow * 272 + lane * 4];
            float v[4];
            #pragma unroll
            for (int k = 0; k < 4; k++) v[k] = (nv[k] + gv[tt][k]) * 0.5f;   // /TAU
            float m = fmaxf(fmaxf(v[0], v[1]), fmaxf(v[2], v[3]));
            #pragma unroll
            for (int off = 1; off < 64; off <<= 1) m = fmaxf(m, __shfl_xor(m, off));
            float sm = 0.f;
            #pragma unroll
            for (int k = 0; k < 4; k++) { v[k] = __expf(v[k] - m); sm += v[k]; }
            #pragma unroll
            for (int off = 1; off < 64; off <<= 1) sm += __shfl_xor(sm, off);
            float inv = 1.0f / sm;
            f32x4 pv;
            #pragma unroll
            for (int k = 0; k < 4; k++) pv[k] = v[k] * inv;
            *(f32x4*)(onb + (size_t)tl * 256 + lane * 4) = pv;   // 16B store
            unsigned long long hv =
                  (unsigned long long)f2bf(pv[0])
                | ((unsigned long long)f2bf(pv[1]) << 16)
                | ((unsigned long long)f2bf(pv[2]) << 32)
                | ((unsigned long long)f2bf(pv[3]) << 48);
            *(unsigned long long*)(smem + ((tl * 512 + lane * 8) ^ ((tl & 7) << 4))) = hv;
        }
        if (c == 0) {
            __syncthreads();   // chunk0 sN2 reads done
            #pragma unroll
            for (int p = 0; p < 4; p++) {
                int n = n0 + 64 * p;
                #pragma unroll
                for (int e = 0; e < 4; e++) sN2[(4 * jj + e) * 272 + n] = r1[p][e];
            }
            __syncthreads();
        }
    }
    __syncthreads();   // sA complete

    // ---------- phase B: K-loop (round-5 structure, 1-deep prefetch) -------
    f32x4 acc[2][4];
    #pragma unroll
    for (int mi = 0; mi < 2; mi++)
        #pragma unroll
        for (int ni = 0; ni < 4; ni++) acc[mi][ni] = (f32x4){0.f, 0.f, 0.f, 0.f};

    const unsigned short* Ptb = Pt + (size_t)b * 65536 + hi * 8;

    short8v bcur[4], bnxt[4];
    #pragma unroll
    for (int ni = 0; ni < 4; ni++) {
        int f = w * 64 + ni * 16 + lo;
        bcur[ni] = *(const short8v*)(Ptb + (size_t)f * 256);
    }

    #pragma unroll
    for (int k0 = 0; k0 < 256; k0 += 32) {
        if (k0 < 224) {
            #pragma unroll
            for (int ni = 0; ni < 4; ni++) {
                int f = w * 64 + ni * 16 + lo;
                bnxt[ni] = *(const short8v*)(Ptb + (size_t)f * 256 + k0 + 32);
            }
        }
        int ka = (k0 + hi * 8) * 2;
        short8v a0 = *(short8v*)(smem + (((lo      ) * 512 + ka) ^ ((lo & 7) << 4)));
        short8v a1 = *(short8v*)(smem + (((lo + 16) * 512 + ka) ^ ((lo & 7) << 4)));
        #pragma unroll
        for (int ni = 0; ni < 4; ni++) {
            acc[0][ni] = __builtin_amdgcn_mfma_f32_16x16x32_bf16(a0, bcur[ni], acc[0][ni], 0, 0, 0);
            acc[1][ni] = __builtin_amdgcn_mfma_f32_16x16x32_bf16(a1, bcur[ni], acc[1][ni], 0, 0, 0);
        }
        if (k0 < 224) {
            #pragma unroll
            for (int ni = 0; ni < 4; ni++) bcur[ni] = bnxt[ni];
        }
    }

    // ---------- phase C: epilogue, 2 phases of 16 rows ---------------------
    float* sMono = (float*)smem;      // [16][260] padded stride
    int tf = tid & 63;
    int tm = tid >> 6;
    int pi = tf >> 3, pj = tf & 7;

    #pragma unroll
    for (int mi = 0; mi < 2; mi++) {
        __syncthreads();   // prior reads of smem done
        #pragma unroll
        for (int ni = 0; ni < 4; ni++) {
            int colf = w * 64 + ni * 16 + lo;
            #pragma unroll
            for (int rg = 0; rg < 4; rg++)
                sMono[(hi * 4 + rg) * 260 + colf] = acc[mi][ni][rg];
        }
        __syncthreads();
        int cbase = mi * 16;
        #pragma unroll
        for (int i = 0; i < 4; i++) {
            int ccl  = tm * 4 + i;          // 0..15
            int ccol = cbase + ccl;         // 0..31
            int tbl  = ccol >> 1;
            float4 mv = *(float4*)&sMono[ccl * 260 + tf * 4];
            #pragma unroll
            for (int c = 0; c < 3; c++) {
                float sv = mv.x * sCol[tbl * 12 + c]
                         + mv.y * sCol[tbl * 12 + 3 + c]
                         + mv.z * sCol[tbl * 12 + 6 + c]
                         + mv.w * sCol[tbl * 12 + 9 + c];
                float y = 1.0f / (1.0f + __expf(-sv));
                img[(((size_t)b * 3 + c) * 240 + rr * 8 + pi) * 256 + ccol * 8 + pj] = y;
            }
        }
    }
}

// ---------------- fp32 fallback image kernel (no ws) -----------------------
__global__ __launch_bounds__(256) void k_image_fp32(const float* __restrict__ A,
                                                    const float* __restrict__ P,
                                                    const float* __restrict__ attr,
                                                    const float* __restrict__ pal,
                                                    float* __restrict__ img) {
    int blk = blockIdx.x;
    int r = blk % 30;
    int b = blk / 30;
    int t0 = r * 32;

    __shared__ float sA[32][33];
    __shared__ float sB[32][256];
    __shared__ float sColF[16][12];

    int tid = threadIdx.x;
    if (tid < 192) {
        int tbl = tid / 12;
        int gc  = tid % 12;
        int tb  = (r >> 1) * 16 + tbl;
        const float* at = attr + ((size_t)b * 240 + tb) * 8;
        const float* pl = pal + (size_t)b * 96 + gc;
        float s = 0.f;
        #pragma unroll
        for (int e = 0; e < 8; e++) s += at[e] * pl[e * 12];
        sColF[tbl][gc] = s;
    }

    float acc[8][4];
    #pragma unroll
    for (int i = 0; i < 8; i++)
        #pragma unroll
        for (int j = 0; j < 4; j++) acc[i][j] = 0.f;

    int tf = tid & 63;
    int tm = tid >> 6;

    const float* Ab = A + ((size_t)b * 960 + t0) * 256;
    const float* Pb = P + (size_t)b * 65536;

    for (int k0 = 0; k0 < 256; k0 += 32) {
        __syncthreads();
        #pragma unroll
        for (int i = 0; i < 4; i++) {
            int li = tid + i * 256;
            int tl = li >> 5, kk = li & 31;
            sA[tl][kk] = Ab[(size_t)tl * 256 + k0 + kk];
        }
        #pragma unroll
        for (int i = 0; i < 8; i++) {
            int li = tid + i * 256;
            int kk = li >> 6, ff = (li & 63) * 4;
            *(float4*)&sB[kk][ff] = *(const float4*)&Pb[(size_t)(k0 + kk) * 256 + ff];
        }
        __syncthreads();
        #pragma unroll
        for (int kk = 0; kk < 32; kk++) {
            float4 bv = *(float4*)&sB[kk][tf * 4];
            #pragma unroll
            for (int i = 0; i < 8; i++) {
                float av = sA[tm * 8 + i][kk];
                acc[i][0] += av * bv.x;
                acc[i][1] += av * bv.y;
                acc[i][2] += av * bv.z;
                acc[i][3] += av * bv.w;
            }
        }
    }

    int pi = tf >> 3, pj = tf & 7;
    #pragma unroll
    for (int i = 0; i < 8; i++) {
        int cc  = tm * 8 + i;
        int tbl = cc >> 1;
        #pragma unroll
        for (int c = 0; c < 3; c++) {
            float s = acc[i][0] * sColF[tbl][c]
                    + acc[i][1] * sColF[tbl][3 + c]
                    + acc[i][2] * sColF[tbl][6 + c]
                    + acc[i][3] * sColF[tbl][9 + c];
            float y = 1.0f / (1.0f + expf(-s));
            img[(((size_t)b * 3 + c) * 240 + r * 8 + pi) * 256 + cc * 8 + pj] = y;
        }
    }
}

extern "C" void kernel_launch(void* const* d_in, const int* in_sizes, int n_in,
                              void* d_out, int out_size, void* d_ws, size_t ws_size,
                              hipStream_t stream) {
    const float* names       = (const float*)d_in[0];
    const float* patterns    = (const float*)d_in[1];
    const float* attributes  = (const float*)d_in[2];
    const float* palettes    = (const float*)d_in[3];
    const float* gumbel_n    = (const float*)d_in[4];
    const float* gumbel_a    = (const float*)d_in[5];
    float* out = (float*)d_out;

    float* out_img   = out + O_IMG;
    float* out_names = out + O_NAMES;
    float* out_p     = out + O_P;
    float* out_attr  = out + O_ATTR;
    float* out_pal   = out + O_PAL;

    const size_t PT_BYTES = 128ULL * 256 * 256 * 2;   // 16.78 MB bf16 P^T
    bool use_mfma = (ws_size >= PT_BYTES) && (d_ws != nullptr);

    if (use_mfma) {
        unsigned short* Pt = (unsigned short*)d_ws;
        k_pattern2<true><<<1024, 256, 0, stream>>>(patterns, out_p, Pt);
        k_attr<<<120, 256, 0, stream>>>(attributes, gumbel_a, palettes, out_attr, out_pal);
        k_fused<<<3840, 256, 0, stream>>>(names, gumbel_n, Pt, out_attr, palettes,
                                          out_names, out_img);
    } else {
        k_pattern2<false><<<1024, 256, 0, stream>>>(patterns, out_p, nullptr);
        k_names<<<128 * 60, 256, 0, stream>>>(names, gumbel_n, out_names);
        k_attr<<<120, 256, 0, stream>>>(attributes, gumbel_a, palettes, out_attr, out_pal);
        k_image_fp32<<<128 * 30, 256, 0, stream>>>(out_names, out_p, out_attr, palettes, out_img);
    }
}